// Round 1
// baseline (204.070 us; speedup 1.0000x reference)
//
#include <hip/hip_runtime.h>

#define NH 16
#define HD 64
#define WIN 256
#define BB 2
#define SS 4096
#define EE 1024

typedef __attribute__((ext_vector_type(8))) short short8;
typedef __attribute__((ext_vector_type(4))) float floatx4;
typedef __attribute__((ext_vector_type(4))) unsigned short ushort4v;

__device__ inline unsigned short f2bf(float f) {
    unsigned u = __builtin_bit_cast(unsigned, f);
    u += 0x7fffu + ((u >> 16) & 1u);
    return (unsigned short)(u >> 16);
}

// ---------------- pass 0: f32 -> bf16 convert of X and W's into d_out scratch
__global__ __launch_bounds__(256)
void cvt_kernel(const float* __restrict__ X,
                const float* __restrict__ W0,
                const float* __restrict__ W1,
                const float* __restrict__ W2,
                unsigned short* __restrict__ out)
{
    size_t idx = (size_t)blockIdx.x * 256 + threadIdx.x;   // float4 index
    const size_t X4 = 2097152, W4 = 262144;                // float4 counts
    const float* src; unsigned short* dst; size_t off;
    if (idx < X4)                { src = X;  dst = out;            off = idx; }
    else if (idx < X4 + W4)      { src = W0; dst = out + 8388608;  off = idx - X4; }
    else if (idx < X4 + 2 * W4)  { src = W1; dst = out + 9437184;  off = idx - X4 - W4; }
    else                         { src = W2; dst = out + 10485760; off = idx - X4 - 2 * W4; }
    float4 v = ((const float4*)src)[off];
    ushort4 u;
    u.x = f2bf(v.x); u.y = f2bf(v.y); u.z = f2bf(v.z); u.w = f2bf(v.w);
    ((ushort4*)dst)[off] = u;
}

// ---------------- pass 1: bf16 GEMM, 256x256 tile, BK=64, 8-phase schedule
// (T1 XCD swizzle + T2 LDS XOR swizzle + T3/T4 counted-vmcnt pipeline + T5 setprio)
// 512 threads = 8 waves (2M x 4N), per-wave 128x64 C. LDS 128KB: 2 K-tile bufs,
// each buf = A[256][64] + B[256][64] bf16 stored as 4 half-slots of 16KB.
// Swizzle: LDS[row][chunk c] holds global [row][c ^ (row&7)] (16B chunks),
// staged by pre-swizzling the per-lane GLOBAL address (global_load_lds dest
// must stay linear), read back with the same XOR on the ds_read address.
__global__ __launch_bounds__(512, 2)
void qkv_gemm8(const unsigned short* __restrict__ Xb,
               const unsigned short* __restrict__ WbAll,
               const float* __restrict__ b0,
               const float* __restrict__ b1,
               const float* __restrict__ b2,
               unsigned short* __restrict__ Qo,
               unsigned short* __restrict__ Ko,
               unsigned short* __restrict__ Vo)
{
    const int id = blockIdx.x;                 // 0..383
    const int swz = (id & 7) * 48 + (id >> 3); // bijective XCD swizzle (384 % 8 == 0)
    const int mtile = swz / 12;                // 0..31 : 4 consecutive m-tiles per XCD
    const int rem = swz - mtile * 12;
    const int mode = rem >> 2;                 // 0..2  (Q,K,V)
    const int ntile = rem & 3;                 // 0..3

    const unsigned short* Wm = WbAll + (size_t)mode * 1048576;
    const float* bm = (mode == 0) ? b0 : (mode == 1) ? b1 : b2;
    unsigned short* outp = (mode == 0) ? Qo : (mode == 1) ? Ko : Vo;
    const int m0 = mtile * 256;
    const int n0 = ntile * 256;

    const int t = threadIdx.x;
    const int lane = t & 63;
    const int w = t >> 6;        // wave 0..7
    const int wm = w >> 2;       // 0..1  (row half of C)
    const int wn = w & 3;        // 0..3  (64-col group of C)
    const int lg = lane >> 4, lc = lane & 15;

    __shared__ __attribute__((aligned(16))) unsigned short smem[65536]; // 128 KiB

    // slot(buf, ab, half) base = ((buf*2+ab)*2+half)*8192 ushorts (16KB each)
#define STAGE8(ab, half, ktile)                                                        \
    {                                                                                  \
        unsigned short* bse_ = smem + ((((ktile) & 1) * 2 + (ab)) * 2 + (half)) * 8192;\
        _Pragma("unroll")                                                              \
        for (int i_ = 0; i_ < 2; ++i_) {                                               \
            const int rl_ = (i_ * 8 + w) * 8 + (lane >> 3);                            \
            const int cs_ = (lane & 7) ^ (lane >> 3);                                  \
            const unsigned short* src_ = ((ab) ? Wm : Xb) +                            \
                (size_t)(((ab) ? n0 : m0) + (half) * 128 + rl_) * EE +                 \
                (ktile) * 64 + cs_ * 8;                                                \
            __builtin_amdgcn_global_load_lds(                                          \
                (const __attribute__((address_space(1))) unsigned int*)src_,           \
                (__attribute__((address_space(3))) unsigned int*)(bse_ + (i_ * 8 + w) * 512), \
                16, 0, 0);                                                             \
        }                                                                              \
    }

    const int swk0 = ((0 + lg) ^ (lc & 7)) * 8;   // kh=0 swizzled chunk (ushorts)
    const int swk1 = ((4 + lg) ^ (lc & 7)) * 8;   // kh=1

#define LDA8(buf, mq, m, kh) \
    (*(const short8*)(smem + ((buf) * 4 + wm) * 8192 + ((mq) * 64 + (m) * 16 + lc) * 64 + ((kh) ? swk1 : swk0)))
#define LDB8(buf, nq, nn, kh) \
    (*(const short8*)(smem + ((buf) * 4 + 2 + (wn >> 1)) * 8192 + ((wn & 1) * 4096 + ((nq) * 32 + (nn) * 16 + lc) * 64) + ((kh) ? swk1 : swk0)))

#define RDA(buf, mq)                                         \
    _Pragma("unroll")                                        \
    for (int m_ = 0; m_ < 4; ++m_) {                         \
        af[m_][0] = LDA8(buf, mq, m_, 0);                    \
        af[m_][1] = LDA8(buf, mq, m_, 1);                    \
    }
#define RDB(buf, nq)                                         \
    _Pragma("unroll")                                        \
    for (int n_ = 0; n_ < 2; ++n_) {                         \
        bf[(nq) * 2 + n_][0] = LDB8(buf, nq, n_, 0);         \
        bf[(nq) * 2 + n_][1] = LDB8(buf, nq, n_, 1);         \
    }

#define MFMAQ(MQ, NQ)                                                               \
    __builtin_amdgcn_s_setprio(1);                                                  \
    _Pragma("unroll")                                                               \
    for (int m_ = 0; m_ < 4; ++m_) {                                                \
        _Pragma("unroll")                                                           \
        for (int n_ = 0; n_ < 2; ++n_) {                                            \
            acc[(MQ) * 4 + m_][(NQ) * 2 + n_] = __builtin_amdgcn_mfma_f32_16x16x32_bf16( \
                af[m_][0], bf[(NQ) * 2 + n_][0], acc[(MQ) * 4 + m_][(NQ) * 2 + n_], 0, 0, 0); \
            acc[(MQ) * 4 + m_][(NQ) * 2 + n_] = __builtin_amdgcn_mfma_f32_16x16x32_bf16( \
                af[m_][1], bf[(NQ) * 2 + n_][1], acc[(MQ) * 4 + m_][(NQ) * 2 + n_], 0, 0, 0); \
        }                                                                           \
    }                                                                               \
    __builtin_amdgcn_s_setprio(0);

    floatx4 acc[8][4];
#pragma unroll
    for (int i = 0; i < 8; ++i)
#pragma unroll
        for (int j = 0; j < 4; ++j)
            acc[i][j] = (floatx4)0.0f;

    short8 af[4][2], bf[4][2];

    // prologue: stage K-tile 0 fully + first half of K-tile 1 (order matters
    // for the counted-vmcnt scheme: ring order is B1,A1 | B0,A0,B1,A1 | B0,A0)
    STAGE8(1, 0, 0) STAGE8(0, 0, 0) STAGE8(1, 1, 0) STAGE8(0, 1, 0)
    STAGE8(1, 0, 1) STAGE8(0, 0, 1)
    asm volatile("s_waitcnt vmcnt(4)" ::: "memory");  // K-tile 0 landed
    __builtin_amdgcn_s_barrier();

#pragma unroll 1
    for (int J = 0; J < 8; ++J) {
        const int kb = 2 * J;
        // ---- phase 0: tile kb (buf0), quadrant (mq0,nq0) ----
        RDA(0, 0) RDB(0, 0)
        STAGE8(1, 1, kb + 1)
        __builtin_amdgcn_s_barrier();
        MFMAQ(0, 0)
        __builtin_amdgcn_s_barrier();
        // ---- phase 1: (mq0,nq1) ----
        RDB(0, 1)
        STAGE8(0, 1, kb + 1)
        __builtin_amdgcn_s_barrier();
        MFMAQ(0, 1)
        __builtin_amdgcn_s_barrier();
        // ---- phase 2: (mq1,nq1) ----
        RDA(0, 1)
        if (J < 7) STAGE8(1, 0, kb + 2)
        __builtin_amdgcn_s_barrier();
        MFMAQ(1, 1)
        __builtin_amdgcn_s_barrier();
        // ---- phase 3: (mq1,nq0), B kept in regs from phase 0 ----
        if (J < 7) STAGE8(0, 0, kb + 2)
        __builtin_amdgcn_s_barrier();
        MFMAQ(1, 0)
        if (J < 7) { asm volatile("s_waitcnt vmcnt(4)" ::: "memory"); }
        else       { asm volatile("s_waitcnt vmcnt(0)" ::: "memory"); }
        __builtin_amdgcn_s_barrier();
        // ---- phase 4: tile kb+1 (buf1), (mq0,nq0) ----
        RDA(1, 0) RDB(1, 0)
        if (J < 7) STAGE8(1, 1, kb + 2)
        __builtin_amdgcn_s_barrier();
        MFMAQ(0, 0)
        __builtin_amdgcn_s_barrier();
        // ---- phase 5: (mq0,nq1) ----
        RDB(1, 1)
        if (J < 7) STAGE8(0, 1, kb + 2)
        __builtin_amdgcn_s_barrier();
        MFMAQ(0, 1)
        __builtin_amdgcn_s_barrier();
        // ---- phase 6: (mq1,nq1) ----
        RDA(1, 1)
        if (J < 7) STAGE8(1, 0, kb + 3)
        __builtin_amdgcn_s_barrier();
        MFMAQ(1, 1)
        __builtin_amdgcn_s_barrier();
        // ---- phase 7: (mq1,nq0) ----
        if (J < 7) STAGE8(0, 0, kb + 3)
        __builtin_amdgcn_s_barrier();
        MFMAQ(1, 0)
        if (J < 7) { asm volatile("s_waitcnt vmcnt(4)" ::: "memory"); }
        __builtin_amdgcn_s_barrier();
    }

    // ---------------- epilogue: 2-pass LDS transpose, stride 264 (16B-aligned)
    const float qscale = (mode == 0) ? 0.125f : 1.0f;
    const int CST = 264;
#pragma unroll 1
    for (int p = 0; p < 2; ++p) {
        __syncthreads();
        if (mode < 2) {
            if (wm == p) {
#pragma unroll
                for (int nt = 0; nt < 4; ++nt) {
                    float bias = bm[n0 + wn * 64 + nt * 16 + lc];
#pragma unroll
                    for (int mt = 0; mt < 8; ++mt)
#pragma unroll
                        for (int r = 0; r < 4; ++r) {
                            int row = mt * 16 + lg * 4 + r;        // 0..127
                            int col = wn * 64 + nt * 16 + lc;      // 0..255
                            smem[row * CST + col] = f2bf((acc[mt][nt][r] + bias) * qscale);
                        }
                }
            }
        } else {
            if ((wn >> 1) == p) {
#pragma unroll
                for (int nt = 0; nt < 4; ++nt) {
                    float bias = bm[n0 + wn * 64 + nt * 16 + lc];
#pragma unroll
                    for (int mt = 0; mt < 8; ++mt) {
                        ushort4v pk;
#pragma unroll
                        for (int r = 0; r < 4; ++r)
                            pk[r] = f2bf(acc[mt][nt][r] + bias);
                        int coll = (wn & 1) * 64 + nt * 16 + lc;   // 0..127
                        int mrow = wm * 128 + mt * 16 + lg * 4;    // 0..252
                        *(ushort4v*)(&smem[coll * CST + mrow]) = pk;
                    }
                }
            }
        }
        __syncthreads();
#pragma unroll
        for (int q = 0; q < 8; ++q) {
            int c = q * 512 + t;
            int row = c >> 5;
            int j = c & 31;
            uint4 val = *(const uint4*)(&smem[row * CST + j * 8]);
            if (mode < 2) {
                int m = m0 + p * 128 + row;
                int bb_ = m >> 12, s = m & (SS - 1);
                int n = n0 + j * 8;
                int hh = n >> 6, dd = n & 63;
                *(uint4*)(outp + (((size_t)bb_ * NH + hh) * SS + s) * HD + dd) = val;
            } else {
                int n = n0 + p * 128 + row;
                int hh = n >> 6, dd = n & 63;
                int m = m0 + j * 8;
                int bb_ = m >> 12, s = m & (SS - 1);
                *(uint4*)(outp + (((size_t)bb_ * NH + hh) * HD + dd) * SS + s) = val;
            }
        }
    }
#undef STAGE8
#undef LDA8
#undef LDB8
#undef RDA
#undef RDB
#undef MFMAQ
}

// ---------------- pass 2: banded flash attention, unnormalized streaming softmax
__global__ __launch_bounds__(256, 2)
void swa_kernel(const unsigned short* __restrict__ Qp_,
                const unsigned short* __restrict__ Kp_,
                const unsigned short* __restrict__ Vp_,
                float* __restrict__ outp)
{
    const int h = blockIdx.x;
    const int q0 = blockIdx.y * 128;
    const int b = blockIdx.z;
    const int t = threadIdx.x, lane = t & 63, wv = t >> 6;
    const int lg = lane >> 4, lc = lane & 15;
    const size_t bh = (size_t)b * NH + h;
    const unsigned short* Qp = Qp_ + bh * (size_t)SS * HD;
    const unsigned short* Kp = Kp_ + bh * (size_t)SS * HD;
    const unsigned short* Vp = Vp_ + bh * (size_t)HD * SS;
    const int qbase = q0 + wv * 32;

    short8 qf[2][2];
#pragma unroll
    for (int rt = 0; rt < 2; ++rt)
#pragma unroll
        for (int hh = 0; hh < 2; ++hh)
            qf[rt][hh] = *(const short8*)(Qp + (size_t)(qbase + rt * 16 + lc) * HD + hh * 32 + lg * 8);

    floatx4 o[2][4];
    float lsum[2][4];
#pragma unroll
    for (int rt = 0; rt < 2; ++rt)
#pragma unroll
        for (int i = 0; i < 4; ++i) { o[rt][i] = (floatx4)0.0f; lsum[rt][i] = 0.0f; }

    __shared__ __attribute__((aligned(16))) unsigned short kvs[2][2][4096];
    __shared__ __attribute__((aligned(16))) unsigned short Ps[4][2][16][72];

    const int kbeg = (q0 >= WIN) ? (q0 - WIN) : 0;
    const int kend = (q0 + 128 + WIN <= SS) ? (q0 + 128 + WIN) : SS;

    const int sr = lane >> 3;
    const int sj = lane & 7;
    const int swz = (sj ^ sr) * 8;

#define STAGE(buf, k0_)                                                              \
    {                                                                                \
        _Pragma("unroll")                                                            \
        for (int i = 0; i < 2; ++i) {                                                \
            int rbase = 16 * wv + i * 8;                                             \
            const unsigned short* ks = Kp + (size_t)((k0_) + rbase + sr) * HD + swz; \
            const unsigned short* vs = Vp + (size_t)(rbase + sr) * SS + (k0_) + swz; \
            __builtin_amdgcn_global_load_lds(                                        \
                (const __attribute__((address_space(1))) unsigned int*)ks,           \
                (__attribute__((address_space(3))) unsigned int*)&kvs[buf][0][rbase * 64], 16, 0, 0); \
            __builtin_amdgcn_global_load_lds(                                        \
                (const __attribute__((address_space(1))) unsigned int*)vs,           \
                (__attribute__((address_space(3))) unsigned int*)&kvs[buf][1][rbase * 64], 16, 0, 0); \
        }                                                                            \
    }

    STAGE(0, kbeg)

    int cur = 0;
    for (int k0 = kbeg; k0 < kend; k0 += 64, cur ^= 1) {
        __syncthreads();
        bool active = (k0 + 63 >= qbase - WIN) && (k0 <= qbase + 31 + WIN);
        short8 kc[4][2], vf[4][2];
        if (active) {
#pragma unroll
            for (int nt = 0; nt < 4; ++nt)
#pragma unroll
                for (int hh = 0; hh < 2; ++hh) {
                    int row = nt * 16 + lc;
                    kc[nt][hh] = *(const short8*)(&kvs[cur][0][row * 64 + (((hh * 4 + lg) ^ (row & 7)) * 8)]);
                    vf[nt][hh] = *(const short8*)(&kvs[cur][1][row * 64 + (((hh * 4 + lg) ^ (row & 7)) * 8)]);
                }
        }
        if (k0 + 64 < kend) STAGE(cur ^ 1, k0 + 64)
        if (!active) continue;

        bool fullband = (k0 >= qbase - 225) && (k0 <= qbase + 193);

        floatx4 sc[2][4];
#pragma unroll
        for (int rt = 0; rt < 2; ++rt)
#pragma unroll
            for (int nt = 0; nt < 4; ++nt) {
                floatx4 z = (floatx4)0.0f;
                z = __builtin_amdgcn_mfma_f32_16x16x32_bf16(qf[rt][0], kc[nt][0], z, 0, 0, 0);
                sc[rt][nt] = __builtin_amdgcn_mfma_f32_16x16x32_bf16(qf[rt][1], kc[nt][1], z, 0, 0, 0);
            }
#pragma unroll
        for (int rt = 0; rt < 2; ++rt)
#pragma unroll
            for (int nt = 0; nt < 4; ++nt)
#pragma unroll
                for (int r = 0; r < 4; ++r)
                    sc[rt][nt][r] = __expf(sc[rt][nt][r]);
        if (!fullband) {
#pragma unroll
            for (int rt = 0; rt < 2; ++rt)
#pragma unroll
                for (int nt = 0; nt < 4; ++nt) {
                    int kk = k0 + nt * 16 + lc;
#pragma unroll
                    for (int r = 0; r < 4; ++r) {
                        int dq = (qbase + rt * 16 + lg * 4 + r) - kk;
                        if (dq > WIN || dq < -WIN) sc[rt][nt][r] = 0.0f;
                    }
                }
        }
#pragma unroll
        for (int rt = 0; rt < 2; ++rt)
#pragma unroll
            for (int r = 0; r < 4; ++r)
                lsum[rt][r] += (sc[rt][0][r] + sc[rt][1][r]) + (sc[rt][2][r] + sc[rt][3][r]);
#pragma unroll
        for (int rt = 0; rt < 2; ++rt)
#pragma unroll
            for (int nt = 0; nt < 4; ++nt)
#pragma unroll
                for (int r = 0; r < 4; ++r)
                    Ps[wv][rt][lg * 4 + r][nt * 16 + lc] = f2bf(sc[rt][nt][r]);
#pragma unroll
        for (int rt = 0; rt < 2; ++rt) {
            short8 pa0 = *(const short8*)(&Ps[wv][rt][lc][lg * 8]);
            short8 pa1 = *(const short8*)(&Ps[wv][rt][lc][32 + lg * 8]);
#pragma unroll
            for (int nt2 = 0; nt2 < 4; ++nt2) {
                o[rt][nt2] = __builtin_amdgcn_mfma_f32_16x16x32_bf16(pa0, vf[nt2][0], o[rt][nt2], 0, 0, 0);
                o[rt][nt2] = __builtin_amdgcn_mfma_f32_16x16x32_bf16(pa1, vf[nt2][1], o[rt][nt2], 0, 0, 0);
            }
        }
    }

#pragma unroll
    for (int rt = 0; rt < 2; ++rt)
#pragma unroll
        for (int r = 0; r < 4; ++r) {
            float rs = lsum[rt][r];
#pragma unroll
            for (int off = 1; off < 16; off <<= 1)
                rs += __shfl_xor(rs, off, 64);
            lsum[rt][r] = 1.0f / rs;
        }
#pragma unroll
    for (int rt = 0; rt < 2; ++rt)
#pragma unroll
        for (int nt2 = 0; nt2 < 4; ++nt2)
#pragma unroll
            for (int r = 0; r < 4; ++r) {
                int q = qbase + rt * 16 + lg * 4 + r;
                int d = nt2 * 16 + lc;
                outp[((size_t)b * SS + q) * EE + h * HD + d] = o[rt][nt2][r] * lsum[rt][r];
            }
}

extern "C" void kernel_launch(void* const* d_in, const int* in_sizes, int n_in,
                              void* d_out, int out_size, void* d_ws, size_t ws_size,
                              hipStream_t stream) {
    const float* X  = (const float*)d_in[0];
    const float* Wq = (const float*)d_in[1];
    const float* bq = (const float*)d_in[2];
    const float* Wk = (const float*)d_in[3];
    const float* bk = (const float*)d_in[4];
    const float* Wv = (const float*)d_in[5];
    const float* bv = (const float*)d_in[6];

    const size_t qkv_elems = (size_t)BB * NH * SS * HD;   // 8,388,608 bf16 each
    unsigned short* Qw = (unsigned short*)d_ws;
    unsigned short* Kw = Qw + qkv_elems;
    unsigned short* Vw = Kw + qkv_elems;

    unsigned short* cvt = (unsigned short*)d_out;
    const unsigned short* Xb = cvt;
    const unsigned short* WbAll = cvt + 8388608;

    cvt_kernel<<<dim3(11264), 256, 0, stream>>>(X, Wq, Wk, Wv, cvt);
    qkv_gemm8<<<dim3(384), 512, 0, stream>>>(
        Xb, WbAll, bq, bk, bv, Qw, Kw, Vw);
    swa_kernel<<<dim3(NH, SS / 128, BB), 256, 0, stream>>>(Qw, Kw, Vw, (float*)d_out);
}

// Round 2
// 198.674 us; speedup vs baseline: 1.0272x; 1.0272x over previous
//
#include <hip/hip_runtime.h>

#define NH 16
#define HD 64
#define WIN 256
#define BB 2
#define SS 4096
#define EE 1024

typedef __attribute__((ext_vector_type(8))) short short8;
typedef __attribute__((ext_vector_type(4))) float floatx4;
typedef __attribute__((ext_vector_type(4))) unsigned short ushort4v;

__device__ inline unsigned short f2bf(float f) {
    unsigned u = __builtin_bit_cast(unsigned, f);
    u += 0x7fffu + ((u >> 16) & 1u);
    return (unsigned short)(u >> 16);
}

// ---------------- pass 0: f32 -> bf16 convert of X and W's into d_out scratch
__global__ __launch_bounds__(256)
void cvt_kernel(const float* __restrict__ X,
                const float* __restrict__ W0,
                const float* __restrict__ W1,
                const float* __restrict__ W2,
                unsigned short* __restrict__ out)
{
    size_t idx = (size_t)blockIdx.x * 256 + threadIdx.x;   // float4 index
    const size_t X4 = 2097152, W4 = 262144;                // float4 counts
    const float* src; unsigned short* dst; size_t off;
    if (idx < X4)                { src = X;  dst = out;            off = idx; }
    else if (idx < X4 + W4)      { src = W0; dst = out + 8388608;  off = idx - X4; }
    else if (idx < X4 + 2 * W4)  { src = W1; dst = out + 9437184;  off = idx - X4 - W4; }
    else                         { src = W2; dst = out + 10485760; off = idx - X4 - 2 * W4; }
    float4 v = ((const float4*)src)[off];
    ushort4 u;
    u.x = f2bf(v.x); u.y = f2bf(v.y); u.z = f2bf(v.z); u.w = f2bf(v.w);
    ((ushort4*)dst)[off] = u;
}

// ---------------- pass 1: bf16 GEMM, BK=64, LDS-transposed coalesced epilogue.
// (reverted to the proven 128^2 / 4-blocks-per-CU structure: 63.5us, 813 TF)
__global__ __launch_bounds__(256, 4)
void qkv_gemm4(const unsigned short* __restrict__ Xb,
               const unsigned short* __restrict__ WbAll,
               const float* __restrict__ b0,
               const float* __restrict__ b1,
               const float* __restrict__ b2,
               unsigned short* __restrict__ Qo,
               unsigned short* __restrict__ Ko,
               unsigned short* __restrict__ Vo)
{
    const int id = blockIdx.x;           // 0..1535
    const int xcd = id & 7;
    const int rest = id >> 3;            // 0..191
    const int ytile = xcd + 8 * (rest & 7);   // 0..63, ytile%8 == xcd
    const int nm = rest >> 3;            // 0..23
    const int ntile = nm & 7;            // 0..7
    const int mode = nm >> 3;            // 0..2

    const unsigned short* Wm = WbAll + (size_t)mode * 1048576;
    const float* bm = (mode == 0) ? b0 : (mode == 1) ? b1 : b2;
    unsigned short* outp = (mode == 0) ? Qo : (mode == 1) ? Ko : Vo;

    const int m0 = ytile * 128;
    const int n0 = ntile * 128;
    const int t = threadIdx.x;
    const int lane = t & 63;
    const int wv = t >> 6;
    const int wm = wv >> 1, wn = wv & 1;
    const int lg = lane >> 4, lc = lane & 15;

    __shared__ __attribute__((aligned(16))) unsigned short smem[16384];
    unsigned short* As[2] = { smem, smem + 4096 };
    unsigned short* Bs[2] = { smem + 8192, smem + 12288 };

    const int srow = lane >> 2;
    const int scol = (lane & 3) * 8;

    floatx4 acc[4][4];
#pragma unroll
    for (int i = 0; i < 4; ++i)
#pragma unroll
        for (int j = 0; j < 4; ++j)
            acc[i][j] = (floatx4)0.0f;

    for (int kt = 0; kt < EE; kt += 64) {
        if (kt) __syncthreads();
#pragma unroll
        for (int half = 0; half < 2; ++half) {
#pragma unroll
            for (int seg = 0; seg < 2; ++seg) {
                int r0 = wv * 32 + seg * 16;
                const unsigned short* asrc =
                    Xb + (size_t)(m0 + r0 + srow) * EE + kt + half * 32 + scol;
                const unsigned short* bsrc =
                    Wm + (size_t)(n0 + r0 + srow) * EE + kt + half * 32 + scol;
                __builtin_amdgcn_global_load_lds(
                    (const __attribute__((address_space(1))) unsigned int*)asrc,
                    (__attribute__((address_space(3))) unsigned int*)&As[half][r0 * 32], 16, 0, 0);
                __builtin_amdgcn_global_load_lds(
                    (const __attribute__((address_space(1))) unsigned int*)bsrc,
                    (__attribute__((address_space(3))) unsigned int*)&Bs[half][r0 * 32], 16, 0, 0);
            }
        }
        __syncthreads();

#pragma unroll
        for (int half = 0; half < 2; ++half) {
            short8 af[4], bfr[4];
#pragma unroll
            for (int mt = 0; mt < 4; ++mt)
                af[mt] = *(const short8*)(&As[half][(wm * 64 + mt * 16 + lc) * 32 + lg * 8]);
#pragma unroll
            for (int nt = 0; nt < 4; ++nt)
                bfr[nt] = *(const short8*)(&Bs[half][(wn * 64 + nt * 16 + lc) * 32 + lg * 8]);
#pragma unroll
            for (int mt = 0; mt < 4; ++mt)
#pragma unroll
                for (int nt = 0; nt < 4; ++nt)
                    acc[mt][nt] = __builtin_amdgcn_mfma_f32_16x16x32_bf16(
                        af[mt], bfr[nt], acc[mt][nt], 0, 0, 0);
        }
    }

    const int CST = 136;
    const float qscale = (mode == 0) ? 0.125f : 1.0f;
#pragma unroll
    for (int p = 0; p < 2; ++p) {
        __syncthreads();
        if (mode < 2) {
            if (wm == p) {
#pragma unroll
                for (int nt = 0; nt < 4; ++nt) {
                    float bias = bm[n0 + wn * 64 + nt * 16 + lc];
#pragma unroll
                    for (int mt = 0; mt < 4; ++mt)
#pragma unroll
                        for (int r = 0; r < 4; ++r) {
                            int ml = mt * 16 + lg * 4 + r;
                            int nl = wn * 64 + nt * 16 + lc;
                            smem[ml * CST + nl] = f2bf((acc[mt][nt][r] + bias) * qscale);
                        }
                }
            }
        } else {
            if (wn == p) {
#pragma unroll
                for (int nt = 0; nt < 4; ++nt) {
                    float bias = bm[n0 + p * 64 + nt * 16 + lc];
#pragma unroll
                    for (int mt = 0; mt < 4; ++mt) {
                        ushort4v pk;
#pragma unroll
                        for (int r = 0; r < 4; ++r)
                            pk[r] = f2bf(acc[mt][nt][r] + bias);
                        int nl = nt * 16 + lc;
                        int col = wm * 64 + mt * 16 + lg * 4;
                        *(ushort4v*)(&smem[nl * CST + col]) = pk;
                    }
                }
            }
        }
        __syncthreads();
#pragma unroll
        for (int q = 0; q < 4; ++q) {
            int c = q * 256 + t;
            int row = c >> 4;
            int j = c & 15;
            uint4 val = *(const uint4*)(&smem[row * CST + j * 8]);
            if (mode < 2) {
                int m = m0 + p * 64 + row;
                int bb = m >> 12, s = m & (SS - 1);
                int n = n0 + j * 8;
                int hh = n >> 6, dd = n & 63;
                *(uint4*)(outp + (((size_t)bb * NH + hh) * SS + s) * HD + dd) = val;
            } else {
                int n = n0 + p * 64 + row;
                int hh = n >> 6, dd = n & 63;
                int m = m0 + j * 8;
                int bb = m >> 12, s = m & (SS - 1);
                *(uint4*)(outp + (((size_t)bb * NH + hh) * HD + dd) * SS + s) = val;
            }
        }
    }
}

// ---------------- pass 2: banded flash attention, unnormalized streaming softmax
// QBLK=256 (8 waves x 32 q-rows, 512 threads): K/V re-fetch ratio drops 5x -> 3x.
// Per-wave structure identical to the proven QBLK=128 version.
__global__ __launch_bounds__(512, 2)
void swa_kernel(const unsigned short* __restrict__ Qp_,
                const unsigned short* __restrict__ Kp_,
                const unsigned short* __restrict__ Vp_,
                float* __restrict__ outp)
{
    const int h = blockIdx.x;
    const int q0 = blockIdx.y * 256;
    const int b = blockIdx.z;
    const int t = threadIdx.x, lane = t & 63, wv = t >> 6;  // wv 0..7
    const int lg = lane >> 4, lc = lane & 15;
    const size_t bh = (size_t)b * NH + h;
    const unsigned short* Qp = Qp_ + bh * (size_t)SS * HD;
    const unsigned short* Kp = Kp_ + bh * (size_t)SS * HD;
    const unsigned short* Vp = Vp_ + bh * (size_t)HD * SS;
    const int qbase = q0 + wv * 32;

    short8 qf[2][2];
#pragma unroll
    for (int rt = 0; rt < 2; ++rt)
#pragma unroll
        for (int hh = 0; hh < 2; ++hh)
            qf[rt][hh] = *(const short8*)(Qp + (size_t)(qbase + rt * 16 + lc) * HD + hh * 32 + lg * 8);

    floatx4 o[2][4];
    float lsum[2][4];
#pragma unroll
    for (int rt = 0; rt < 2; ++rt)
#pragma unroll
        for (int i = 0; i < 4; ++i) { o[rt][i] = (floatx4)0.0f; lsum[rt][i] = 0.0f; }

    __shared__ __attribute__((aligned(16))) unsigned short kvs[2][2][4096];
    __shared__ __attribute__((aligned(16))) unsigned short Ps[8][2][16][72];

    const int kbeg = (q0 >= WIN) ? (q0 - WIN) : 0;
    const int kend = (q0 + 256 + WIN <= SS) ? (q0 + 256 + WIN) : SS;

    const int sr = lane >> 3;
    const int sj = lane & 7;
    const int swz = (sj ^ sr) * 8;

    // 8 waves x 8 rows = 64 rows per K-tile (K) and 64 d-rows (V)
#define STAGE(buf, k0_)                                                              \
    {                                                                                \
        const int rbase = 8 * wv;                                                    \
        const unsigned short* ks = Kp + (size_t)((k0_) + rbase + sr) * HD + swz;     \
        const unsigned short* vs = Vp + (size_t)(rbase + sr) * SS + (k0_) + swz;     \
        __builtin_amdgcn_global_load_lds(                                            \
            (const __attribute__((address_space(1))) unsigned int*)ks,               \
            (__attribute__((address_space(3))) unsigned int*)&kvs[buf][0][rbase * 64], 16, 0, 0); \
        __builtin_amdgcn_global_load_lds(                                            \
            (const __attribute__((address_space(1))) unsigned int*)vs,               \
            (__attribute__((address_space(3))) unsigned int*)&kvs[buf][1][rbase * 64], 16, 0, 0); \
    }

    STAGE(0, kbeg)

    int cur = 0;
    for (int k0 = kbeg; k0 < kend; k0 += 64, cur ^= 1) {
        __syncthreads();
        bool active = (k0 + 63 >= qbase - WIN) && (k0 <= qbase + 31 + WIN);
        short8 kc[4][2], vf[4][2];
        if (active) {
#pragma unroll
            for (int nt = 0; nt < 4; ++nt)
#pragma unroll
                for (int hh = 0; hh < 2; ++hh) {
                    int row = nt * 16 + lc;
                    kc[nt][hh] = *(const short8*)(&kvs[cur][0][row * 64 + (((hh * 4 + lg) ^ (row & 7)) * 8)]);
                    vf[nt][hh] = *(const short8*)(&kvs[cur][1][row * 64 + (((hh * 4 + lg) ^ (row & 7)) * 8)]);
                }
        }
        if (k0 + 64 < kend) STAGE(cur ^ 1, k0 + 64)
        if (!active) continue;

        bool fullband = (k0 >= qbase - 225) && (k0 <= qbase + 193);

        floatx4 sc[2][4];
        __builtin_amdgcn_s_setprio(1);
#pragma unroll
        for (int rt = 0; rt < 2; ++rt)
#pragma unroll
            for (int nt = 0; nt < 4; ++nt) {
                floatx4 z = (floatx4)0.0f;
                z = __builtin_amdgcn_mfma_f32_16x16x32_bf16(qf[rt][0], kc[nt][0], z, 0, 0, 0);
                sc[rt][nt] = __builtin_amdgcn_mfma_f32_16x16x32_bf16(qf[rt][1], kc[nt][1], z, 0, 0, 0);
            }
        __builtin_amdgcn_s_setprio(0);
#pragma unroll
        for (int rt = 0; rt < 2; ++rt)
#pragma unroll
            for (int nt = 0; nt < 4; ++nt)
#pragma unroll
                for (int r = 0; r < 4; ++r)
                    sc[rt][nt][r] = __expf(sc[rt][nt][r]);
        if (!fullband) {
#pragma unroll
            for (int rt = 0; rt < 2; ++rt)
#pragma unroll
                for (int nt = 0; nt < 4; ++nt) {
                    int kk = k0 + nt * 16 + lc;
#pragma unroll
                    for (int r = 0; r < 4; ++r) {
                        int dq = (qbase + rt * 16 + lg * 4 + r) - kk;
                        if (dq > WIN || dq < -WIN) sc[rt][nt][r] = 0.0f;
                    }
                }
        }
#pragma unroll
        for (int rt = 0; rt < 2; ++rt)
#pragma unroll
            for (int r = 0; r < 4; ++r)
                lsum[rt][r] += (sc[rt][0][r] + sc[rt][1][r]) + (sc[rt][2][r] + sc[rt][3][r]);
#pragma unroll
        for (int rt = 0; rt < 2; ++rt)
#pragma unroll
            for (int nt = 0; nt < 4; ++nt)
#pragma unroll
                for (int r = 0; r < 4; ++r)
                    Ps[wv][rt][lg * 4 + r][nt * 16 + lc] = f2bf(sc[rt][nt][r]);
#pragma unroll
        for (int rt = 0; rt < 2; ++rt) {
            short8 pa0 = *(const short8*)(&Ps[wv][rt][lc][lg * 8]);
            short8 pa1 = *(const short8*)(&Ps[wv][rt][lc][32 + lg * 8]);
            __builtin_amdgcn_s_setprio(1);
#pragma unroll
            for (int nt2 = 0; nt2 < 4; ++nt2) {
                o[rt][nt2] = __builtin_amdgcn_mfma_f32_16x16x32_bf16(pa0, vf[nt2][0], o[rt][nt2], 0, 0, 0);
                o[rt][nt2] = __builtin_amdgcn_mfma_f32_16x16x32_bf16(pa1, vf[nt2][1], o[rt][nt2], 0, 0, 0);
            }
            __builtin_amdgcn_s_setprio(0);
        }
    }

#pragma unroll
    for (int rt = 0; rt < 2; ++rt)
#pragma unroll
        for (int r = 0; r < 4; ++r) {
            float rs = lsum[rt][r];
#pragma unroll
            for (int off = 1; off < 16; off <<= 1)
                rs += __shfl_xor(rs, off, 64);
            lsum[rt][r] = 1.0f / rs;
        }
#pragma unroll
    for (int rt = 0; rt < 2; ++rt)
#pragma unroll
        for (int nt2 = 0; nt2 < 4; ++nt2)
#pragma unroll
            for (int r = 0; r < 4; ++r) {
                int q = qbase + rt * 16 + lg * 4 + r;
                int d = nt2 * 16 + lc;
                outp[((size_t)b * SS + q) * EE + h * HD + d] = o[rt][nt2][r] * lsum[rt][r];
            }
}

extern "C" void kernel_launch(void* const* d_in, const int* in_sizes, int n_in,
                              void* d_out, int out_size, void* d_ws, size_t ws_size,
                              hipStream_t stream) {
    const float* X  = (const float*)d_in[0];
    const float* Wq = (const float*)d_in[1];
    const float* bq = (const float*)d_in[2];
    const float* Wk = (const float*)d_in[3];
    const float* bk = (const float*)d_in[4];
    const float* Wv = (const float*)d_in[5];
    const float* bv = (const float*)d_in[6];

    const size_t qkv_elems = (size_t)BB * NH * SS * HD;   // 8,388,608 bf16 each
    unsigned short* Qw = (unsigned short*)d_ws;
    unsigned short* Kw = Qw + qkv_elems;
    unsigned short* Vw = Kw + qkv_elems;

    unsigned short* cvt = (unsigned short*)d_out;
    const unsigned short* Xb = cvt;
    const unsigned short* WbAll = cvt + 8388608;

    cvt_kernel<<<dim3(11264), 256, 0, stream>>>(X, Wq, Wk, Wv, cvt);
    qkv_gemm4<<<dim3(1536), 256, 0, stream>>>(
        Xb, WbAll, bq, bk, bv, Qw, Kw, Vw);
    swa_kernel<<<dim3(NH, SS / 256, BB), 512, 0, stream>>>(Qw, Kw, Vw, (float*)d_out);
}